// Round 10
// baseline (143.739 us; speedup 1.0000x reference)
//
#include <hip/hip_runtime.h>
#include <hip/hip_bf16.h>

typedef __attribute__((ext_vector_type(8))) __bf16 bf16x8;
typedef __attribute__((ext_vector_type(4))) float f32x4;
typedef unsigned short u16;

#define NB 8192
#define ND 128
#define NCHUNK 16
#define NEGINF (-__builtin_inff())
#define POSINF (__builtin_inff())

__device__ inline u16 f2b(float f){
  __hip_bfloat16 h = __float2bfloat16(f);
  return *reinterpret_cast<u16*>(&h);
}

// ---- prep: fp32 -> bf16, colp[row] = (sq, p=1/(1-sq), sq*p, lab_bits) ------
// also zeroes the final-reduction cells so fin_k's atomic finish is
// graph-replay-safe (stream order: prep -> gram -> fin every iteration).
extern "C" __global__ __launch_bounds__(256)
void prep_k(const float* __restrict__ x, const int* __restrict__ lab,
            u16* __restrict__ xb, float4* __restrict__ colp,
            float* __restrict__ gred, unsigned int* __restrict__ done)
{
  if (blockIdx.x == 0 && threadIdx.x == 0){
    gred[0] = 0.0f; gred[1] = 0.0f; *done = 0u;
  }
  const int tid = blockIdx.x * 256 + threadIdx.x;
  const int row = tid >> 5;           // 32 threads per row
  const int sub = tid & 31;
  const float4 v = reinterpret_cast<const float4*>(x)[row * 32 + sub];
  float s = v.x*v.x + v.y*v.y + v.z*v.z + v.w*v.w;
  #pragma unroll
  for (int m = 1; m < 32; m <<= 1) s += __shfl_xor(s, m, 32);
  ushort4 o;
  o.x = f2b(v.x); o.y = f2b(v.y); o.z = f2b(v.z); o.w = f2b(v.w);
  reinterpret_cast<ushort4*>(xb)[row * 32 + sub] = o;
  if (sub == 0){
    const float p = 1.0f / (1.0f - s);
    colp[row] = make_float4(s, p, s * p, __int_as_float(lab[row]));
  }
}

// ---- main: bf16 MFMA gram tiles + streaming row max/min --------------------
// grid (64, 16): x = 128-row tile, y = 512-col chunk. 4 waves x 32 rows.
// ROUND-10 STRUCTURE: NO LDS, NO BARRIERS. Rounds 6-9 proved the 2-phase
// barrier pipeline is the floor (41-44us pinned across occupancy 20->33%,
// VALU trims, addressing trims; r9 higher occupancy was WORSE). xb (2MB)
// is L2-resident and each block's 4 waves re-read the same 16KB half-tile
// (L1-catchable), so B fragments are loaded DIRECTLY to registers from
// global: deletes all __syncthreads / global_load_lds / vmcnt(0) drains.
// Waves free-run; TLP hides L2 latency. mt=2 row-reuse per B frag kept
// (r9 lesson: halving rows/wave doubles B traffic). 1-deep ks prefetch
// (bfA/bfB, static indices per rule #20). (256,3): reg peak ~156 < 170.
// Carried: incremental pointers (r6), uniform-wid s_cbranch (r7).
extern "C" __global__ __launch_bounds__(256, 3)
void gram_k(const u16* __restrict__ xb, const float4* __restrict__ colp,
            float* __restrict__ ppos, float* __restrict__ pneg)
{
  const int wid  = __builtin_amdgcn_readfirstlane(threadIdx.x >> 6);
  const int lane = threadIdx.x & 63;
  const int m16  = lane & 15;
  const int quad = lane >> 4;
  const int R0  = blockIdx.x * 128;
  const int C0  = blockIdx.y * 512;
  const int WR0 = R0 + wid * 32;     // wave-uniform (SGPR)

  // A fragments in registers: A[m=lane&15][k=quad*8+j]
  bf16x8 afrag[2][4];
  #pragma unroll
  for (int mt = 0; mt < 2; ++mt){
    const u16* arow = xb + (WR0 + mt*16 + m16) * ND;
    #pragma unroll
    for (int ks = 0; ks < 4; ++ks)
      afrag[mt][ks] = *reinterpret_cast<const bf16x8*>(arow + ks*32 + quad*8);
  }

  // per-row (C/D row = quad*4 + r) params
  float sqi[8]; int labi[8];
  #pragma unroll
  for (int mt = 0; mt < 2; ++mt)
    #pragma unroll
    for (int r = 0; r < 4; ++r){
      const float4 cp = colp[WR0 + mt*16 + quad*4 + r];
      sqi[mt*4+r]  = cp.x;
      labi[mt*4+r] = __float_as_int(cp.w);
    }

  float vpos[8], vneg[8];
  #pragma unroll
  for (int i = 0; i < 8; ++i){ vpos[i] = NEGINF; vneg[i] = POSINF; }

  // B fragment pointers, one per nt (nt*16 cols apart = 4096B: exceeds the
  // 13-bit signed imm, so 4 pointers). Per-lane address for (s,ks,nt):
  // (C0 + s*64 + nt*16 + m16)*ND + (ks*4+quad)*8 -> base + s*16KB + ks*64B.
  // ks*64 folds into the load offset imm; pointers advance +16KB per phase.
  const u16* bp0 = xb + (C0 +  0 + m16) * ND + quad*8;
  const u16* bp1 = xb + (C0 + 16 + m16) * ND + quad*8;
  const u16* bp2 = xb + (C0 + 32 + m16) * ND + quad*8;
  const u16* bp3 = xb + (C0 + 48 + m16) * ND + quad*8;
  // epilogue column-param pointer: advanced by +64 per phase
  const float4* cpp = colp + C0 + m16;

  #pragma unroll 1
  for (int s = 0; s < 8; ++s){
    const int CT0 = C0 + s * 64;
    f32x4 acc[2][4];
    #pragma unroll
    for (int mt = 0; mt < 2; ++mt)
      #pragma unroll
      for (int nt = 0; nt < 4; ++nt){
        f32x4 z = {0.f, 0.f, 0.f, 0.f};
        acc[mt][nt] = z;
      }

    // 1-deep ks software pipeline: load slot for ks+1 while MFMAing ks.
    // All indices compile-time (named bfA/bfB, unrolled) -> stays in regs.
    bf16x8 bfA0, bfA1, bfA2, bfA3, bfB0, bfB1, bfB2, bfB3;
    bfA0 = *reinterpret_cast<const bf16x8*>(bp0 + 0*32);
    bfA1 = *reinterpret_cast<const bf16x8*>(bp1 + 0*32);
    bfA2 = *reinterpret_cast<const bf16x8*>(bp2 + 0*32);
    bfA3 = *reinterpret_cast<const bf16x8*>(bp3 + 0*32);

    // ks = 0 (prefetch ks=1)
    bfB0 = *reinterpret_cast<const bf16x8*>(bp0 + 1*32);
    bfB1 = *reinterpret_cast<const bf16x8*>(bp1 + 1*32);
    bfB2 = *reinterpret_cast<const bf16x8*>(bp2 + 1*32);
    bfB3 = *reinterpret_cast<const bf16x8*>(bp3 + 1*32);
    acc[0][0] = __builtin_amdgcn_mfma_f32_16x16x32_bf16(afrag[0][0], bfA0, acc[0][0], 0, 0, 0);
    acc[1][0] = __builtin_amdgcn_mfma_f32_16x16x32_bf16(afrag[1][0], bfA0, acc[1][0], 0, 0, 0);
    acc[0][1] = __builtin_amdgcn_mfma_f32_16x16x32_bf16(afrag[0][0], bfA1, acc[0][1], 0, 0, 0);
    acc[1][1] = __builtin_amdgcn_mfma_f32_16x16x32_bf16(afrag[1][0], bfA1, acc[1][1], 0, 0, 0);
    acc[0][2] = __builtin_amdgcn_mfma_f32_16x16x32_bf16(afrag[0][0], bfA2, acc[0][2], 0, 0, 0);
    acc[1][2] = __builtin_amdgcn_mfma_f32_16x16x32_bf16(afrag[1][0], bfA2, acc[1][2], 0, 0, 0);
    acc[0][3] = __builtin_amdgcn_mfma_f32_16x16x32_bf16(afrag[0][0], bfA3, acc[0][3], 0, 0, 0);
    acc[1][3] = __builtin_amdgcn_mfma_f32_16x16x32_bf16(afrag[1][0], bfA3, acc[1][3], 0, 0, 0);

    // ks = 1 (prefetch ks=2 into A slots)
    bfA0 = *reinterpret_cast<const bf16x8*>(bp0 + 2*32);
    bfA1 = *reinterpret_cast<const bf16x8*>(bp1 + 2*32);
    bfA2 = *reinterpret_cast<const bf16x8*>(bp2 + 2*32);
    bfA3 = *reinterpret_cast<const bf16x8*>(bp3 + 2*32);
    acc[0][0] = __builtin_amdgcn_mfma_f32_16x16x32_bf16(afrag[0][1], bfB0, acc[0][0], 0, 0, 0);
    acc[1][0] = __builtin_amdgcn_mfma_f32_16x16x32_bf16(afrag[1][1], bfB0, acc[1][0], 0, 0, 0);
    acc[0][1] = __builtin_amdgcn_mfma_f32_16x16x32_bf16(afrag[0][1], bfB1, acc[0][1], 0, 0, 0);
    acc[1][1] = __builtin_amdgcn_mfma_f32_16x16x32_bf16(afrag[1][1], bfB1, acc[1][1], 0, 0, 0);
    acc[0][2] = __builtin_amdgcn_mfma_f32_16x16x32_bf16(afrag[0][1], bfB2, acc[0][2], 0, 0, 0);
    acc[1][2] = __builtin_amdgcn_mfma_f32_16x16x32_bf16(afrag[1][1], bfB2, acc[1][2], 0, 0, 0);
    acc[0][3] = __builtin_amdgcn_mfma_f32_16x16x32_bf16(afrag[0][1], bfB3, acc[0][3], 0, 0, 0);
    acc[1][3] = __builtin_amdgcn_mfma_f32_16x16x32_bf16(afrag[1][1], bfB3, acc[1][3], 0, 0, 0);

    // ks = 2 (prefetch ks=3 into B slots)
    bfB0 = *reinterpret_cast<const bf16x8*>(bp0 + 3*32);
    bfB1 = *reinterpret_cast<const bf16x8*>(bp1 + 3*32);
    bfB2 = *reinterpret_cast<const bf16x8*>(bp2 + 3*32);
    bfB3 = *reinterpret_cast<const bf16x8*>(bp3 + 3*32);
    acc[0][0] = __builtin_amdgcn_mfma_f32_16x16x32_bf16(afrag[0][2], bfA0, acc[0][0], 0, 0, 0);
    acc[1][0] = __builtin_amdgcn_mfma_f32_16x16x32_bf16(afrag[1][2], bfA0, acc[1][0], 0, 0, 0);
    acc[0][1] = __builtin_amdgcn_mfma_f32_16x16x32_bf16(afrag[0][2], bfA1, acc[0][1], 0, 0, 0);
    acc[1][1] = __builtin_amdgcn_mfma_f32_16x16x32_bf16(afrag[1][2], bfA1, acc[1][1], 0, 0, 0);
    acc[0][2] = __builtin_amdgcn_mfma_f32_16x16x32_bf16(afrag[0][2], bfA2, acc[0][2], 0, 0, 0);
    acc[1][2] = __builtin_amdgcn_mfma_f32_16x16x32_bf16(afrag[1][2], bfA2, acc[1][2], 0, 0, 0);
    acc[0][3] = __builtin_amdgcn_mfma_f32_16x16x32_bf16(afrag[0][2], bfA3, acc[0][3], 0, 0, 0);
    acc[1][3] = __builtin_amdgcn_mfma_f32_16x16x32_bf16(afrag[1][2], bfA3, acc[1][3], 0, 0, 0);

    // ks = 3
    acc[0][0] = __builtin_amdgcn_mfma_f32_16x16x32_bf16(afrag[0][3], bfB0, acc[0][0], 0, 0, 0);
    acc[1][0] = __builtin_amdgcn_mfma_f32_16x16x32_bf16(afrag[1][3], bfB0, acc[1][0], 0, 0, 0);
    acc[0][1] = __builtin_amdgcn_mfma_f32_16x16x32_bf16(afrag[0][3], bfB1, acc[0][1], 0, 0, 0);
    acc[1][1] = __builtin_amdgcn_mfma_f32_16x16x32_bf16(afrag[1][3], bfB1, acc[1][1], 0, 0, 0);
    acc[0][2] = __builtin_amdgcn_mfma_f32_16x16x32_bf16(afrag[0][3], bfB2, acc[0][2], 0, 0, 0);
    acc[1][2] = __builtin_amdgcn_mfma_f32_16x16x32_bf16(afrag[1][3], bfB2, acc[1][2], 0, 0, 0);
    acc[0][3] = __builtin_amdgcn_mfma_f32_16x16x32_bf16(afrag[0][3], bfB3, acc[0][3], 0, 0, 0);
    acc[1][3] = __builtin_amdgcn_mfma_f32_16x16x32_bf16(afrag[1][3], bfB3, acc[1][3], 0, 0, 0);

    // epilogue: u = (sq_i + sq_j - 2g) * p_j  (no interior clamp; fin clamps)
    // colp via incremental pointer; tilediag SGPR-uniform -> s_cbranch.
    #pragma unroll
    for (int nt = 0; nt < 4; ++nt){
      const float4 cp = cpp[nt * 16];
      const float pj   = cp.y;
      const float spj  = cp.z;
      const int   labj = __float_as_int(cp.w);
      const float n2pj = -2.0f * pj;
      #pragma unroll
      for (int mt = 0; mt < 2; ++mt){
        const bool tilediag = (WR0 + mt*16) == (CT0 + nt*16);
        if (!tilediag){
          #pragma unroll
          for (int r = 0; r < 4; ++r){
            const int idx = mt*4 + r;
            const float u = fmaf(n2pj, acc[mt][nt][r], fmaf(sqi[idx], pj, spj));
            const bool sm = (labi[idx] == labj);
            vpos[idx] = fmaxf(vpos[idx], sm ? u : NEGINF);
            vneg[idx] = fminf(vneg[idx], sm ? POSINF : u);
          }
        } else {
          #pragma unroll
          for (int r = 0; r < 4; ++r){
            const int idx = mt*4 + r;
            const float u = fmaf(n2pj, acc[mt][nt][r], fmaf(sqi[idx], pj, spj));
            const bool sm = (labi[idx] == labj);
            const bool dg = (m16 == quad*4 + r);
            vpos[idx] = fmaxf(vpos[idx], (sm && !dg) ? u : NEGINF);
            vneg[idx] = fminf(vneg[idx], sm ? POSINF : u);
          }
        }
      }
    }
    cpp += 64;                            // next half-tile's column params
    bp0 += 64 * ND; bp1 += 64 * ND; bp2 += 64 * ND; bp3 += 64 * ND;
  }

  // row i lives in the 16 lanes of one quad-group: reduce across them
  #pragma unroll
  for (int i = 0; i < 8; ++i){
    #pragma unroll
    for (int m = 1; m < 16; m <<= 1){
      vpos[i] = fmaxf(vpos[i], __shfl_xor(vpos[i], m, 16));
      vneg[i] = fminf(vneg[i], __shfl_xor(vneg[i], m, 16));
    }
  }
  if (m16 == 0){
    #pragma unroll
    for (int i = 0; i < 8; ++i){
      const int row = WR0 + (i >> 2)*16 + quad*4 + (i & 3);
      ppos[blockIdx.y * NB + row] = vpos[i];
      pneg[blockIdx.y * NB + row] = vneg[i];
    }
  }
}

// ---- finalize (fused): 64 blocks x 128 rows -> atomic finish ---------------
extern "C" __global__ __launch_bounds__(128)
void fin_k(const float* __restrict__ ppos, const float* __restrict__ pneg,
           const float4* __restrict__ colp, float* __restrict__ gred,
           unsigned int* __restrict__ done, float* __restrict__ out)
{
  const int row = blockIdx.x * 128 + threadIdx.x;
  float up = NEGINF, un = POSINF;
  #pragma unroll
  for (int c = 0; c < NCHUNK; ++c){
    up = fmaxf(up, ppos[c * NB + row]);
    un = fminf(un, pneg[c * NB + row]);
  }
  const bool hp = (up > NEGINF);
  const bool hn = (un < POSINF);
  const float pi = colp[row].y;
  float dp = 0.0f, dn = 0.0f;
  // arccosh(1+t) = log1p(t + sqrt(t*(t+2))), t clamped at 1e-7 (matches ref)
  if (hp){ float t = fmaxf(2.0f * up * pi, 1e-7f); dp = log1pf(t + sqrtf(t * (t + 2.0f))); }
  if (hn){ float t = fmaxf(2.0f * un * pi, 1e-7f); dn = log1pf(t + sqrtf(t * (t + 2.0f))); }
  float lsum = (hp && hn) ? fmaxf(dp - dn + 0.5f, 0.0f) : 0.0f;
  float lcnt = (hp && hn) ? 1.0f : 0.0f;
  #pragma unroll
  for (int m = 1; m < 64; m <<= 1){
    lsum += __shfl_xor(lsum, m, 64);
    lcnt += __shfl_xor(lcnt, m, 64);
  }
  __shared__ float2 s_p[2];
  if ((threadIdx.x & 63) == 0) s_p[threadIdx.x >> 6] = make_float2(lsum, lcnt);
  __syncthreads();
  if (threadIdx.x == 0){
    const float bs = s_p[0].x + s_p[1].x;
    const float bc = s_p[0].y + s_p[1].y;
    atomicAdd(&gred[0], bs);
    atomicAdd(&gred[1], bc);
    __threadfence();
    const unsigned int prev = atomicAdd(done, 1u);
    if (prev == 63u){                      // last block: all adds visible
      __threadfence();
      const float s = atomicAdd(&gred[0], 0.0f);   // read via atomic (L2)
      const float c = atomicAdd(&gred[1], 0.0f);
      out[0] = (c > 0.0f) ? (s / c) : 0.0f;
    }
  }
}

extern "C" void kernel_launch(void* const* d_in, const int* in_sizes, int n_in,
                              void* d_out, int out_size, void* d_ws, size_t ws_size,
                              hipStream_t stream)
{
  const float* x  = (const float*)d_in[0];
  const int* lab  = (const int*)d_in[1];
  char* ws = (char*)d_ws;
  u16*    xb   = (u16*)ws;                                        // 2 MB
  float4* colp = (float4*)(ws + (size_t)2*1024*1024);             // 128 KB
  float*  ppos = (float*)(ws + (size_t)2*1024*1024 + 128*1024);   // 512 KB
  float*  pneg = (float*)(ws + (size_t)2*1024*1024 + 128*1024 + 512*1024); // 512 KB
  float*  gred = (float*)(ws + (size_t)2*1024*1024 + 128*1024 + 1024*1024); // 8 B
  unsigned int* done = (unsigned int*)(ws + (size_t)2*1024*1024 + 128*1024
                                          + 1024*1024 + 64);      // 4 B

  hipLaunchKernelGGL(prep_k, dim3(1024), dim3(256), 0, stream, x, lab, xb, colp,
                     gred, done);
  hipLaunchKernelGGL(gram_k, dim3(64, NCHUNK), dim3(256), 0, stream,
                     xb, colp, ppos, pneg);
  hipLaunchKernelGGL(fin_k, dim3(64), dim3(128), 0, stream, ppos, pneg, colp,
                     gred, done, (float*)d_out);
}

// Round 11
// 112.097 us; speedup vs baseline: 1.2823x; 1.2823x over previous
//
#include <hip/hip_runtime.h>
#include <hip/hip_bf16.h>

typedef __attribute__((ext_vector_type(8))) __bf16 bf16x8;
typedef __attribute__((ext_vector_type(4))) float f32x4;
typedef unsigned short u16;

#define NB 8192
#define ND 128
#define NEGINF (-__builtin_inff())
#define POSINF (__builtin_inff())

__device__ inline u16 f2b(float f){
  __hip_bfloat16 h = __float2bfloat16(f);
  return *reinterpret_cast<u16*>(&h);
}

// ---- prep: fp32 -> bf16, colp[row] = (sq, p=1/(1-sq), sq*p, lab_bits) ------
// also inits the per-row atomic min/max slots (pposI=-inf, pnegI=+inf bits)
// and the final-reduction cells -> whole pipeline is graph-replay-safe
// (stream order: prep -> gram -> fin every iteration).
extern "C" __global__ __launch_bounds__(256)
void prep_k(const float* __restrict__ x, const int* __restrict__ lab,
            u16* __restrict__ xb, float4* __restrict__ colp,
            int* __restrict__ pposI, int* __restrict__ pnegI,
            float* __restrict__ gred, unsigned int* __restrict__ done)
{
  if (blockIdx.x == 0 && threadIdx.x == 0){
    gred[0] = 0.0f; gred[1] = 0.0f; *done = 0u;
  }
  const int tid = blockIdx.x * 256 + threadIdx.x;
  if (tid < NB){
    pposI[tid] = (int)0xFF800000u;   // -inf bits
    pnegI[tid] = (int)0x7F800000u;   // +inf bits
  }
  const int row = tid >> 5;           // 32 threads per row
  const int sub = tid & 31;
  const float4 v = reinterpret_cast<const float4*>(x)[row * 32 + sub];
  float s = v.x*v.x + v.y*v.y + v.z*v.z + v.w*v.w;
  #pragma unroll
  for (int m = 1; m < 32; m <<= 1) s += __shfl_xor(s, m, 32);
  ushort4 o;
  o.x = f2b(v.x); o.y = f2b(v.y); o.z = f2b(v.z); o.w = f2b(v.w);
  reinterpret_cast<ushort4*>(xb)[row * 32 + sub] = o;
  if (sub == 0){
    const float p = 1.0f / (1.0f - s);
    colp[row] = make_float4(s, p, s * p, __int_as_float(lab[row]));
  }
}

// ---- main: bf16 MFMA gram tiles, SYMMETRY-HALVED -----------------------------
// grid (64,16) launched; blocks with chunk < band>>2 exit -> 544 computed
// tiles (53%). Each tile serves BOTH triangles:
//   direct   : row i over cols j,  u_d = d2*p_j  (16-lane reduce as before)
//   transpose: row j over cols i,  u_t = d2*p_i  (reduce over r/mt in-lane +
//              2 shfl_xor over quads; one coalesced wave atomicMax/Min per
//              phase, col = CT0+lane). d2 = max(sq_i+sq_j-2g, 1e-30) matches
//              ref's d2>=0 clamp (fin's 1e-7 t-clamp absorbs the 1e-30) and
//              makes all values POSITIVE -> int-bit atomics are order-correct
//              with -inf/+inf sentinels.
// Coverage: pair (i,j) hits direct if g_j>=g_i, transpose if g_i>=g_j; one
// always holds; duplicates (diag-band tiles) are idempotent under max/min.
// Carried: 2-phase LDS dbuf pipeline (r2/r3), rolled loop (r3), incremental
// pointers (r6), uniform-wid s_cbranch (r7), (256,3) no-spill budget (r3/r8).
extern "C" __global__ __launch_bounds__(256, 3)
void gram_k(const u16* __restrict__ xb, const float4* __restrict__ colp,
            int* __restrict__ pposI, int* __restrict__ pnegI)
{
  const int rb = blockIdx.x;            // row band (128 rows)
  const int cb = blockIdx.y;            // col chunk (512 cols)
  if (cb < (rb >> 2)) return;           // lower-triangle tile: covered by
                                        // the transpose of (cb-rows, rb-cols)
  __shared__ u16 Bt[2][64 * 128];   // 2 x 16 KB double buffer, 256B/col,
                                    // 16B chunks XOR-swizzled by col&15
  const int wid  = __builtin_amdgcn_readfirstlane(threadIdx.x >> 6);
  const int lane = threadIdx.x & 63;
  const int m16  = lane & 15;
  const int quad = lane >> 4;
  const int R0  = rb * 128;
  const int C0  = cb * 512;
  const int WR0 = R0 + wid * 32;     // wave-uniform (SGPR)

  // A fragments in registers: A[m=lane&15][k=quad*8+j]
  bf16x8 afrag[2][4];
  #pragma unroll
  for (int mt = 0; mt < 2; ++mt){
    const u16* arow = xb + (WR0 + mt*16 + m16) * ND;
    #pragma unroll
    for (int ks = 0; ks < 4; ++ks)
      afrag[mt][ks] = *reinterpret_cast<const bf16x8*>(arow + ks*32 + quad*8);
  }

  // per-row (C/D row = quad*4 + r) params: sq_i, p_i, label
  float sqi[8], pii[8]; int labi[8];
  #pragma unroll
  for (int mt = 0; mt < 2; ++mt)
    #pragma unroll
    for (int r = 0; r < 4; ++r){
      const float4 cp = colp[WR0 + mt*16 + quad*4 + r];
      sqi[mt*4+r]  = cp.x;
      pii[mt*4+r]  = cp.y;
      labi[mt*4+r] = __float_as_int(cp.w);
    }

  float vpos[8], vneg[8];
  #pragma unroll
  for (int i = 0; i < 8; ++i){ vpos[i] = NEGINF; vneg[i] = POSINF; }

  // Per-thread staging base pointers, computed ONCE (r6). For chunk c (0..3):
  // brow(c) = wid*16 + c*4 + quad; src(c) = m16 ^ (brow(c) & 15).
  // Advanced by +64*ND after each stage call (stage order s = 0..7).
  const u16* sp0 = xb + (C0 + wid*16 + 0*4 + quad) * ND + (m16 ^ ((0*4 + quad) & 15)) * 8;
  const u16* sp1 = xb + (C0 + wid*16 + 1*4 + quad) * ND + (m16 ^ ((1*4 + quad) & 15)) * 8;
  const u16* sp2 = xb + (C0 + wid*16 + 2*4 + quad) * ND + (m16 ^ ((2*4 + quad) & 15)) * 8;
  const u16* sp3 = xb + (C0 + wid*16 + 3*4 + quad) * ND + (m16 ^ ((3*4 + quad) & 15)) * 8;
  // epilogue column-param pointer: advanced by +64 per compute (s = 0..7)
  const float4* cpp = colp + C0 + m16;

  auto stage = [&](int b){
    __builtin_amdgcn_global_load_lds(
        (__attribute__((address_space(1))) void*)sp0,
        (__attribute__((address_space(3))) void*)(&Bt[b][(wid*4 + 0) * 512]), 16, 0, 0);
    __builtin_amdgcn_global_load_lds(
        (__attribute__((address_space(1))) void*)sp1,
        (__attribute__((address_space(3))) void*)(&Bt[b][(wid*4 + 1) * 512]), 16, 0, 0);
    __builtin_amdgcn_global_load_lds(
        (__attribute__((address_space(1))) void*)sp2,
        (__attribute__((address_space(3))) void*)(&Bt[b][(wid*4 + 2) * 512]), 16, 0, 0);
    __builtin_amdgcn_global_load_lds(
        (__attribute__((address_space(1))) void*)sp3,
        (__attribute__((address_space(3))) void*)(&Bt[b][(wid*4 + 3) * 512]), 16, 0, 0);
    sp0 += 64 * ND; sp1 += 64 * ND; sp2 += 64 * ND; sp3 += 64 * ND;
  };

  auto compute = [&](int s, int b){
    const int CT0 = C0 + s * 64;
    f32x4 acc[2][4];
    #pragma unroll
    for (int mt = 0; mt < 2; ++mt)
      #pragma unroll
      for (int nt = 0; nt < 4; ++nt){
        f32x4 z = {0.f, 0.f, 0.f, 0.f};
        acc[mt][nt] = z;
      }

    #pragma unroll
    for (int ks = 0; ks < 4; ++ks){
      const int t = ks * 4 + quad;                 // 16B chunk index in col
      const u16* bb = &Bt[b][0] + m16 * 128 + ((t ^ m16) * 8);
      #pragma unroll
      for (int nt = 0; nt < 4; ++nt){
        const bf16x8 bfrag = *reinterpret_cast<const bf16x8*>(bb + nt * 2048);
        acc[0][nt] = __builtin_amdgcn_mfma_f32_16x16x32_bf16(afrag[0][ks], bfrag, acc[0][nt], 0, 0, 0);
        acc[1][nt] = __builtin_amdgcn_mfma_f32_16x16x32_bf16(afrag[1][ks], bfrag, acc[1][nt], 0, 0, 0);
      }
    }

    // epilogue: d2 = max(sq_i+sq_j-2g, 1e-30); u_d = d2*p_j -> row i (regs);
    // u_t = d2*p_i -> row j (per-phase transpose partials + atomics).
    float tp[4], tn[4];
    #pragma unroll
    for (int nt = 0; nt < 4; ++nt){
      const float4 cp = cpp[nt * 16];
      const float sqj  = cp.x;
      const float pj   = cp.y;
      const int   labj = __float_as_int(cp.w);
      float tpn = NEGINF, tnn = POSINF;
      #pragma unroll
      for (int mt = 0; mt < 2; ++mt){
        const bool tilediag = (WR0 + mt*16) == (CT0 + nt*16);
        if (!tilediag){
          #pragma unroll
          for (int r = 0; r < 4; ++r){
            const int idx = mt*4 + r;
            float d2 = fmaf(-2.0f, acc[mt][nt][r], sqi[idx] + sqj);
            d2 = fmaxf(d2, 1e-30f);
            const float ud = d2 * pj;
            const float ut = d2 * pii[idx];
            const bool sm = (labi[idx] == labj);
            vpos[idx] = fmaxf(vpos[idx], sm ? ud : NEGINF);
            vneg[idx] = fminf(vneg[idx], sm ? POSINF : ud);
            tpn = fmaxf(tpn, sm ? ut : NEGINF);
            tnn = fminf(tnn, sm ? POSINF : ut);
          }
        } else {
          #pragma unroll
          for (int r = 0; r < 4; ++r){
            const int idx = mt*4 + r;
            float d2 = fmaf(-2.0f, acc[mt][nt][r], sqi[idx] + sqj);
            d2 = fmaxf(d2, 1e-30f);
            const float ud = d2 * pj;
            const float ut = d2 * pii[idx];
            const bool sm = (labi[idx] == labj);
            const bool dg = (m16 == quad*4 + r);
            const bool ps = sm && !dg;
            vpos[idx] = fmaxf(vpos[idx], ps ? ud : NEGINF);
            vneg[idx] = fminf(vneg[idx], sm ? POSINF : ud);
            tpn = fmaxf(tpn, ps ? ut : NEGINF);
            tnn = fminf(tnn, sm ? POSINF : ut);
          }
        }
      }
      tp[nt] = tpn; tn[nt] = tnn;
    }
    // transpose finish: reduce over quads (lane bits 4-5), then lane
    // (quad,m16) writes col CT0+lane (coalesced wave-wide atomic).
    #pragma unroll
    for (int nt = 0; nt < 4; ++nt){
      tp[nt] = fmaxf(tp[nt], __shfl_xor(tp[nt], 16, 64));
      tp[nt] = fmaxf(tp[nt], __shfl_xor(tp[nt], 32, 64));
      tn[nt] = fminf(tn[nt], __shfl_xor(tn[nt], 16, 64));
      tn[nt] = fminf(tn[nt], __shfl_xor(tn[nt], 32, 64));
    }
    const float wp = (quad == 0) ? tp[0] : (quad == 1) ? tp[1]
                   : (quad == 2) ? tp[2] : tp[3];
    const float wn = (quad == 0) ? tn[0] : (quad == 1) ? tn[1]
                   : (quad == 2) ? tn[2] : tn[3];
    atomicMax(pposI + CT0 + lane, __float_as_int(wp));
    atomicMin(pnegI + CT0 + lane, __float_as_int(wn));
    cpp += 64;                            // next half-tile's column params
  };

  // pipelined main loop, ROLLED (r3): half-tiles {2ss,2ss+1} in bufs {0,1}.
  stage(0);                              // s=0 -> buf0
  __syncthreads();                       // drains vmcnt(0): tile 0 ready
  #pragma unroll 1
  for (int ss = 0; ss < 4; ++ss){
    const int s0 = ss * 2;
    stage(1);                            // s0+1 -> buf1
    compute(s0, 0);
    __syncthreads();                     // buf1 staged; buf0 consumed
    if (ss < 3) stage(0);                // s0+2 -> buf0
    compute(s0 + 1, 1);
    if (ss < 3) __syncthreads();         // buf0 staged; buf1 consumed
  }

  // direct finish: row i lives in the 16 lanes of one quad-group
  #pragma unroll
  for (int i = 0; i < 8; ++i){
    #pragma unroll
    for (int m = 1; m < 16; m <<= 1){
      vpos[i] = fmaxf(vpos[i], __shfl_xor(vpos[i], m, 16));
      vneg[i] = fminf(vneg[i], __shfl_xor(vneg[i], m, 16));
    }
  }
  if (m16 == 0){
    #pragma unroll
    for (int i = 0; i < 8; ++i){
      const int row = WR0 + (i >> 2)*16 + quad*4 + (i & 3);
      atomicMax(pposI + row, __float_as_int(vpos[i]));
      atomicMin(pnegI + row, __float_as_int(vneg[i]));
    }
  }
}

// ---- finalize (fused): 64 blocks x 128 rows -> atomic finish ---------------
extern "C" __global__ __launch_bounds__(128)
void fin_k(const int* __restrict__ pposI, const int* __restrict__ pnegI,
           const float4* __restrict__ colp, float* __restrict__ gred,
           unsigned int* __restrict__ done, float* __restrict__ out)
{
  const int row = blockIdx.x * 128 + threadIdx.x;
  const float up = __int_as_float(pposI[row]);
  const float un = __int_as_float(pnegI[row]);
  const bool hp = (up > NEGINF);
  const bool hn = (un < POSINF);
  const float pi = colp[row].y;
  float dp = 0.0f, dn = 0.0f;
  // arccosh(1+t) = log1p(t + sqrt(t*(t+2))), t clamped at 1e-7 (matches ref)
  if (hp){ float t = fmaxf(2.0f * up * pi, 1e-7f); dp = log1pf(t + sqrtf(t * (t + 2.0f))); }
  if (hn){ float t = fmaxf(2.0f * un * pi, 1e-7f); dn = log1pf(t + sqrtf(t * (t + 2.0f))); }
  float lsum = (hp && hn) ? fmaxf(dp - dn + 0.5f, 0.0f) : 0.0f;
  float lcnt = (hp && hn) ? 1.0f : 0.0f;
  #pragma unroll
  for (int m = 1; m < 64; m <<= 1){
    lsum += __shfl_xor(lsum, m, 64);
    lcnt += __shfl_xor(lcnt, m, 64);
  }
  __shared__ float2 s_p[2];
  if ((threadIdx.x & 63) == 0) s_p[threadIdx.x >> 6] = make_float2(lsum, lcnt);
  __syncthreads();
  if (threadIdx.x == 0){
    const float bs = s_p[0].x + s_p[1].x;
    const float bc = s_p[0].y + s_p[1].y;
    atomicAdd(&gred[0], bs);
    atomicAdd(&gred[1], bc);
    __threadfence();
    const unsigned int prev = atomicAdd(done, 1u);
    if (prev == 63u){                      // last block: all adds visible
      __threadfence();
      const float s = atomicAdd(&gred[0], 0.0f);   // read via atomic (L2)
      const float c = atomicAdd(&gred[1], 0.0f);
      out[0] = (c > 0.0f) ? (s / c) : 0.0f;
    }
  }
}

extern "C" void kernel_launch(void* const* d_in, const int* in_sizes, int n_in,
                              void* d_out, int out_size, void* d_ws, size_t ws_size,
                              hipStream_t stream)
{
  const float* x  = (const float*)d_in[0];
  const int* lab  = (const int*)d_in[1];
  char* ws = (char*)d_ws;
  u16*    xb   = (u16*)ws;                                        // 2 MB
  float4* colp = (float4*)(ws + (size_t)2*1024*1024);             // 128 KB
  int*    pposI= (int*)(ws + (size_t)2*1024*1024 + 128*1024);     // 32 KB
  int*    pnegI= (int*)(ws + (size_t)2*1024*1024 + 128*1024 + 512*1024); // 32 KB
  float*  gred = (float*)(ws + (size_t)2*1024*1024 + 128*1024 + 1024*1024); // 8 B
  unsigned int* done = (unsigned int*)(ws + (size_t)2*1024*1024 + 128*1024
                                          + 1024*1024 + 64);      // 4 B

  hipLaunchKernelGGL(prep_k, dim3(1024), dim3(256), 0, stream, x, lab, xb, colp,
                     pposI, pnegI, gred, done);
  hipLaunchKernelGGL(gram_k, dim3(64, 16), dim3(256), 0, stream,
                     xb, colp, pposI, pnegI);
  hipLaunchKernelGGL(fin_k, dim3(64), dim3(128), 0, stream, pposI, pnegI, colp,
                     gred, done, (float*)d_out);
}